// Round 1
// baseline (7783.572 us; speedup 1.0000x reference)
//
#include <hip/hip_runtime.h>
#include <cstdint>
#include <cstddef>

#define BB    512
#define WINN  512
#define DIN   128
#define HIDN  256
#define DOUTN 64
#define PLENN 64
#define G4    1024   // 4*HID
#define KTOT  448    // DOUT + DIN + HID

__device__ __forceinline__ float tanh_fast(float xx) {
  float e = __expf(2.0f * xx);
  return 1.0f - 2.0f / (e + 1.0f);
}
__device__ __forceinline__ float sigmoid_fast(float xx) {
  return 1.0f / (1.0f + __expf(-xx));
}

// ---------------- one-time weight prep (transposes + bias fuse) ----------------
__global__ void prep_weights(const float* __restrict__ W, const float* __restrict__ W_ih,
                             const float* __restrict__ W_hh, const float* __restrict__ b_ih,
                             const float* __restrict__ b_hh, const float* __restrict__ Wd,
                             float* __restrict__ WT, float* __restrict__ WihT,
                             float* __restrict__ Wdt, float* __restrict__ bias)
{
  int i = blockIdx.x * 256 + threadIdx.x;
  // WT[j][v] = W[v][j]   (512 x 128)
  if (i < 512 * 128) { int j = i >> 7, v = i & 127; WT[i] = W[v * 512 + j]; }
  // WihT[k][g]: k<192 -> W_ih[g][k], else W_hh[g][k-192]   (448 x 1024)
  if (i < 448 * 1024) {
    int k = i >> 10, g = i & 1023;
    WihT[i] = (k < 192) ? W_ih[g * 192 + k] : W_hh[g * 256 + (k - 192)];
  }
  // Wdt[h][d] = Wd[d][h]  (256 x 64)
  if (i < 256 * 64) { int h = i >> 6, d = i & 63; Wdt[i] = Wd[d * 256 + h]; }
  if (i < 1024) bias[i] = b_ih[i] + b_hh[i];
}

// ---------------- one-time Uk = einsum('vd,bwd->bvw') ----------------
// Block computes 64 rows (r = b*512+w) x 64 v, K=128 in two 64-wide stages.
__global__ __launch_bounds__(256) void compute_uk(const float* __restrict__ x,
                                                  const float* __restrict__ U,
                                                  float* __restrict__ Uk)
{
  __shared__ float xs[64][69];  // [r][k]
  __shared__ float us[64][69];  // [v][k]
  int tid = threadIdx.x;
  int rblk = blockIdx.x >> 1;
  int vhalf = blockIdx.x & 1;
  int r0g = rblk * 64;
  int v0g = vhalf * 64;
  int b  = r0g >> 9;
  int w0 = r0g & 511;
  int tr = tid & 15, tc = tid >> 4;
  float acc[4][4];
#pragma unroll
  for (int i = 0; i < 4; ++i)
#pragma unroll
    for (int j = 0; j < 4; ++j) acc[i][j] = 0.f;

  for (int ks = 0; ks < 2; ++ks) {
    int k0 = ks * 64;
#pragma unroll
    for (int i = 0; i < 4; ++i) {
      int idx = tid + i * 256;          // 0..1023
      int r = idx >> 4, kq = idx & 15;
      float4 v4 = *(const float4*)(x + (size_t)(r0g + r) * 128 + k0 + kq * 4);
      xs[r][kq * 4 + 0] = v4.x; xs[r][kq * 4 + 1] = v4.y;
      xs[r][kq * 4 + 2] = v4.z; xs[r][kq * 4 + 3] = v4.w;
    }
#pragma unroll
    for (int i = 0; i < 4; ++i) {
      int idx = tid + i * 256;
      int v = idx >> 4, kq = idx & 15;
      float4 v4 = *(const float4*)(U + (size_t)(v0g + v) * 128 + k0 + kq * 4);
      us[v][kq * 4 + 0] = v4.x; us[v][kq * 4 + 1] = v4.y;
      us[v][kq * 4 + 2] = v4.z; us[v][kq * 4 + 3] = v4.w;
    }
    __syncthreads();
#pragma unroll 8
    for (int k = 0; k < 64; ++k) {
      float xr[4], ur[4];
#pragma unroll
      for (int i = 0; i < 4; ++i) xr[i] = xs[tr * 4 + i][k];
#pragma unroll
      for (int j = 0; j < 4; ++j) ur[j] = us[tc * 4 + j][k];
#pragma unroll
      for (int i = 0; i < 4; ++i)
#pragma unroll
        for (int j = 0; j < 4; ++j) acc[i][j] = fmaf(xr[i], ur[j], acc[i][j]);
    }
    __syncthreads();
  }
  // Uk[b][v][w]
#pragma unroll
  for (int j = 0; j < 4; ++j) {
    float4 f0 = make_float4(acc[0][j], acc[1][j], acc[2][j], acc[3][j]);
    float* dst = Uk + ((size_t)b * 128 + v0g + tc * 4 + j) * 512 + w0 + tr * 4;
    *(float4*)dst = f0;
  }
}

// ---------------- per-step attention: Wq, e, softmax, weight-out, ctx ----------------
__global__ __launch_bounds__(512) void attn_step(const float* __restrict__ Uk,
    const float* __restrict__ x, const float* __restrict__ s, const float* __restrict__ c,
    const float* __restrict__ WT, const float* __restrict__ V,
    float* __restrict__ ctx, float* __restrict__ wout, int t)
{
  __shared__ float q[512];
  __shared__ float wqp[4][128];
  __shared__ float wq[128];
  __shared__ float vv[128];
  __shared__ float watt[512];
  __shared__ float red[16];
  __shared__ float cpart[4][128];
  int tid = threadIdx.x;
  int b = blockIdx.x;

  q[tid] = (tid < 256) ? s[b * 256 + tid] : c[b * 256 + (tid - 256)];
  if (tid < 128) vv[tid] = V[tid];
  __syncthreads();

  // Wq[v] = sum_j q[j] * W[v][j], 4-way split over j
  {
    int v = tid & 127, p = tid >> 7;
    float a = 0.f;
    const float* wtp = WT + (size_t)(p * 128) * 128 + v;
#pragma unroll 4
    for (int j = 0; j < 128; ++j) a = fmaf(q[p * 128 + j], wtp[j * 128], a);
    wqp[p][v] = a;
  }
  __syncthreads();
  if (tid < 128) wq[tid] = wqp[0][tid] + wqp[1][tid] + wqp[2][tid] + wqp[3][tid];
  __syncthreads();

  // e[w] = sum_v vv[v] * tanh(wq[v] + Uk[b][v][w]);  w = tid
  float e;
  {
    const float* ukp = Uk + ((size_t)b * 128) * 512 + tid;
    float a = 0.f;
#pragma unroll 4
    for (int v = 0; v < 128; ++v) {
      float u = ukp[(size_t)v * 512];
      float th = tanh_fast(wq[v] + u);
      a = fmaf(vv[v], th, a);
    }
    e = a;
  }

  // softmax over 512 threads
  float m = e;
#pragma unroll
  for (int o = 32; o > 0; o >>= 1) m = fmaxf(m, __shfl_xor(m, o));
  if ((tid & 63) == 0) red[tid >> 6] = m;
  __syncthreads();
  float M = red[0];
#pragma unroll
  for (int i2 = 1; i2 < 8; ++i2) M = fmaxf(M, red[i2]);
  float p = __expf(e - M);
  float ws = p;
#pragma unroll
  for (int o = 32; o > 0; o >>= 1) ws += __shfl_xor(ws, o);
  if ((tid & 63) == 0) red[8 + (tid >> 6)] = ws;
  __syncthreads();
  float S = red[8] + red[9] + red[10] + red[11] + red[12] + red[13] + red[14] + red[15];
  float wv = p / S;
  watt[tid] = wv;
  wout[(size_t)b * PLENN * 512 + (size_t)t * 512 + tid] = wv;
  __syncthreads();

  // ctx[d] = sum_w watt[w] * x[b][w][d]
  {
    int d = tid & 127, ch = tid >> 7;
    const float* xp = x + ((size_t)b * 512 + ch * 128) * 128 + d;
    float a = 0.f;
#pragma unroll 4
    for (int i = 0; i < 128; ++i) a = fmaf(watt[ch * 128 + i], xp[(size_t)i * 128], a);
    cpart[ch][d] = a;
  }
  __syncthreads();
  if (tid < 128)
    ctx[b * 128 + tid] = cpart[0][tid] + cpart[1][tid] + cpart[2][tid] + cpart[3][tid];
}

// ---------------- per-step gates GEMM: [y|ctx|s](512x448) @ WihT(448x1024), split-K x2 ----------------
__global__ __launch_bounds__(256) void gates_gemm(const float* __restrict__ y,
    const float* __restrict__ ctx, const float* __restrict__ s,
    const float* __restrict__ WihT, const float* __restrict__ bias,
    float* __restrict__ g0, float* __restrict__ g1)
{
  __shared__ float As[32][68];  // [k][r]
  __shared__ float Bs[32][68];  // [k][c]
  int tid = threadIdx.x;
  int bm = blockIdx.x;   // 0..7
  int bn = blockIdx.y;   // 0..15
  int kz = blockIdx.z;   // 0..1
  int tr = tid & 15, tc = tid >> 4;
  float acc[4][4];
#pragma unroll
  for (int i = 0; i < 4; ++i)
#pragma unroll
    for (int j = 0; j < 4; ++j) acc[i][j] = 0.f;

  for (int kt = 0; kt < 7; ++kt) {
    int k0 = kz * 224 + kt * 32;
    const float* Ab; int stride, off;
    if (k0 < 64)       { Ab = y;   stride = 64;  off = 0; }
    else if (k0 < 192) { Ab = ctx; stride = 128; off = 64; }
    else               { Ab = s;   stride = 256; off = 192; }
#pragma unroll
    for (int i = 0; i < 8; ++i) {
      int idx = tid + i * 256;        // 0..2047
      int r = idx >> 5, kk = idx & 31;
      As[kk][r] = Ab[(size_t)(bm * 64 + r) * stride + (k0 - off) + kk];
    }
#pragma unroll
    for (int i = 0; i < 8; ++i) {
      int idx = tid + i * 256;
      int kk = idx >> 6, cc = idx & 63;
      Bs[kk][cc] = WihT[(size_t)(k0 + kk) * 1024 + bn * 64 + cc];
    }
    __syncthreads();
#pragma unroll 8
    for (int kk = 0; kk < 32; ++kk) {
      float a4[4], b4[4];
      *(float4*)a4 = *(const float4*)&As[kk][tr * 4];
      *(float4*)b4 = *(const float4*)&Bs[kk][tc * 4];
#pragma unroll
      for (int i = 0; i < 4; ++i)
#pragma unroll
        for (int j = 0; j < 4; ++j) acc[i][j] = fmaf(a4[i], b4[j], acc[i][j]);
    }
    __syncthreads();
  }
  float* dst = kz ? g1 : g0;
#pragma unroll
  for (int i = 0; i < 4; ++i) {
    int bb = bm * 64 + tr * 4 + i;
    int g  = bn * 64 + tc * 4;
    float4 o4;
    o4.x = acc[i][0] + (kz == 0 ? bias[g + 0] : 0.f);
    o4.y = acc[i][1] + (kz == 0 ? bias[g + 1] : 0.f);
    o4.z = acc[i][2] + (kz == 0 ? bias[g + 2] : 0.f);
    o4.w = acc[i][3] + (kz == 0 ? bias[g + 3] : 0.f);
    *(float4*)(dst + (size_t)bb * 1024 + g) = o4;
  }
}

// ---------------- per-step LSTM elementwise + y = s_new @ Wd^T + bd ----------------
__global__ __launch_bounds__(256) void lstm_step(const float* __restrict__ g0,
    const float* __restrict__ g1, float* __restrict__ s, float* __restrict__ c,
    float* __restrict__ y, const float* __restrict__ Wdt, const float* __restrict__ bd,
    float* __restrict__ outy, int t)
{
  __shared__ float ssh[256];
  int b = blockIdx.x, h = threadIdx.x;
  size_t gb = (size_t)b * 1024;
  float gi = g0[gb + h]       + g1[gb + h];
  float gf = g0[gb + 256 + h] + g1[gb + 256 + h];
  float gg = g0[gb + 512 + h] + g1[gb + 512 + h];
  float go = g0[gb + 768 + h] + g1[gb + 768 + h];
  float cv = c[b * 256 + h];
  float cn = sigmoid_fast(gf) * cv + sigmoid_fast(gi) * tanh_fast(gg);
  float sn = sigmoid_fast(go) * tanh_fast(cn);
  c[b * 256 + h] = cn;
  s[b * 256 + h] = sn;
  ssh[h] = sn;
  __syncthreads();
  if (h < 64) {
    float a = bd[h];
#pragma unroll 4
    for (int k = 0; k < 256; ++k) a = fmaf(ssh[k], Wdt[k * 64 + h], a);
    y[b * 64 + h] = a;
    outy[(size_t)b * PLENN * 64 + (size_t)t * 64 + h] = a;
  }
}

extern "C" void kernel_launch(void* const* d_in, const int* in_sizes, int n_in,
                              void* d_out, int out_size, void* d_ws, size_t ws_size,
                              hipStream_t stream)
{
  (void)in_sizes; (void)n_in; (void)out_size; (void)ws_size;
  const float* x    = (const float*)d_in[0];
  // d_in[1] = plength (device scalar; fixed 64 per problem spec)
  const float* V    = (const float*)d_in[2];
  const float* W    = (const float*)d_in[3];
  const float* U    = (const float*)d_in[4];
  const float* W_ih = (const float*)d_in[5];
  const float* W_hh = (const float*)d_in[6];
  const float* b_ih = (const float*)d_in[7];
  const float* b_hh = (const float*)d_in[8];
  const float* Wd   = (const float*)d_in[9];
  const float* bd   = (const float*)d_in[10];

  float* out  = (float*)d_out;
  float* outy = out;                                   // predict_y (B,64,64)
  float* outw = out + (size_t)BB * PLENN * DOUTN;      // weight    (B,64,512)

  float* ws = (float*)d_ws;
  size_t o = 0;
  float* Uk   = ws + o; o += (size_t)BB * DIN * WINN;  // 33.5M floats
  float* WT   = ws + o; o += 512 * 128;
  float* WihT = ws + o; o += 448 * 1024;
  float* Wdt  = ws + o; o += 256 * 64;
  float* bias = ws + o; o += 1024;
  float* sbuf = ws + o; o += (size_t)BB * HIDN;
  float* cbuf = ws + o; o += (size_t)BB * HIDN;
  float* ybuf = ws + o; o += (size_t)BB * DOUTN;
  float* ctx  = ws + o; o += (size_t)BB * DIN;
  float* g0   = ws + o; o += (size_t)BB * G4;
  float* g1   = ws + o; o += (size_t)BB * G4;

  hipMemsetAsync(sbuf, 0, (size_t)BB * HIDN * sizeof(float), stream);
  hipMemsetAsync(cbuf, 0, (size_t)BB * HIDN * sizeof(float), stream);
  hipMemsetAsync(ybuf, 0, (size_t)BB * DOUTN * sizeof(float), stream);

  prep_weights<<<1792, 256, 0, stream>>>(W, W_ih, W_hh, b_ih, b_hh, Wd, WT, WihT, Wdt, bias);
  compute_uk<<<8192, 256, 0, stream>>>(x, U, Uk);

  for (int t = 0; t < PLENN; ++t) {
    attn_step<<<BB, 512, 0, stream>>>(Uk, x, sbuf, cbuf, WT, V, ctx, outw, t);
    gates_gemm<<<dim3(8, 16, 2), 256, 0, stream>>>(ybuf, ctx, sbuf, WihT, bias, g0, g1);
    lstm_step<<<BB, 256, 0, stream>>>(g0, g1, sbuf, cbuf, ybuf, Wdt, bd, outy, t);
  }
}

// Round 2
// 6284.945 us; speedup vs baseline: 1.2384x; 1.2384x over previous
//
#include <hip/hip_runtime.h>
#include <cstdint>
#include <cstddef>

#define BB    512
#define WINN  512
#define DIN   128
#define HIDN  256
#define DOUTN 64
#define PLENN 64
#define G4    1024   // 4*HID

__device__ __forceinline__ float tanh_fast(float xx) {
  float e = __expf(2.0f * xx);
  return 1.0f - 2.0f * __builtin_amdgcn_rcpf(e + 1.0f);
}
__device__ __forceinline__ float sigmoid_fast(float xx) {
  return __builtin_amdgcn_rcpf(1.0f + __expf(-xx));
}
__device__ __forceinline__ ushort f2bf(float f) {
  uint32_t u = __float_as_uint(f);
  return (ushort)((u + 0x7fffu + ((u >> 16) & 1u)) >> 16);
}
__device__ __forceinline__ float bflo(uint32_t u) { return __uint_as_float(u << 16); }
__device__ __forceinline__ float bfhi(uint32_t u) { return __uint_as_float(u & 0xffff0000u); }

// ---------------- one-time weight prep (transposes + bias fuse) ----------------
__global__ void prep_weights(const float* __restrict__ W, const float* __restrict__ W_ih,
                             const float* __restrict__ W_hh, const float* __restrict__ b_ih,
                             const float* __restrict__ b_hh, const float* __restrict__ Wd,
                             float* __restrict__ WT, float* __restrict__ WihT,
                             float* __restrict__ Wdt, float* __restrict__ bias)
{
  int i = blockIdx.x * 256 + threadIdx.x;
  if (i < 512 * 128) { int j = i >> 7, v = i & 127; WT[i] = W[v * 512 + j]; }
  if (i < 448 * 1024) {
    int k = i >> 10, g = i & 1023;
    WihT[i] = (k < 192) ? W_ih[g * 192 + k] : W_hh[g * 256 + (k - 192)];
  }
  if (i < 256 * 64) { int h = i >> 6, d = i & 63; Wdt[i] = Wd[d * 256 + h]; }
  if (i < 1024) bias[i] = b_ih[i] + b_hh[i];
}

// ---------------- one-time x -> bf16 copy ----------------
__global__ __launch_bounds__(256) void convert_x(const float* __restrict__ x,
                                                 ushort* __restrict__ x16)
{
  size_t i = ((size_t)blockIdx.x * 256 + threadIdx.x) * 8;
  float4 a = *(const float4*)(x + i);
  float4 b = *(const float4*)(x + i + 4);
  uint4 o;
  o.x = (uint32_t)f2bf(a.x) | ((uint32_t)f2bf(a.y) << 16);
  o.y = (uint32_t)f2bf(a.z) | ((uint32_t)f2bf(a.w) << 16);
  o.z = (uint32_t)f2bf(b.x) | ((uint32_t)f2bf(b.y) << 16);
  o.w = (uint32_t)f2bf(b.z) | ((uint32_t)f2bf(b.w) << 16);
  *(uint4*)(x16 + i) = o;
}

// ---------------- one-time Uk = einsum('vd,bwd->bvw'), bf16 output ----------------
// LDS layout [k][r] with XOR swizzle: logical (k, r=4*rb+c) at col 4*(rb^(k&3))+c.
__global__ __launch_bounds__(256) void compute_uk(const float* __restrict__ x,
                                                  const float* __restrict__ U,
                                                  ushort* __restrict__ Uk16)
{
  __shared__ float xs[64][68];  // [k][r-swizzled]
  __shared__ float us[64][68];  // [k][v-swizzled]
  int tid = threadIdx.x;
  int rblk = blockIdx.x >> 1;
  int vhalf = blockIdx.x & 1;
  int r0g = rblk * 64;
  int v0g = vhalf * 64;
  int b  = r0g >> 9;
  int w0 = r0g & 511;
  int tr = tid & 15, tc = tid >> 4;
  float acc[4][4];
#pragma unroll
  for (int i = 0; i < 4; ++i)
#pragma unroll
    for (int j = 0; j < 4; ++j) acc[i][j] = 0.f;

  for (int ks = 0; ks < 2; ++ks) {
    int k0 = ks * 64;
#pragma unroll
    for (int i = 0; i < 4; ++i) {
      int idx = tid + i * 256;          // 0..1023
      int r = idx >> 4, kq = idx & 15;  // r 0..63, kq 0..15 (k quad)
      float4 v4 = *(const float4*)(x + (size_t)(r0g + r) * 128 + k0 + kq * 4);
      int rb = r >> 2, cr = r & 3;
      xs[kq * 4 + 0][4 * (rb ^ ((kq * 4 + 0) & 3)) + cr] = v4.x;
      xs[kq * 4 + 1][4 * (rb ^ ((kq * 4 + 1) & 3)) + cr] = v4.y;
      xs[kq * 4 + 2][4 * (rb ^ ((kq * 4 + 2) & 3)) + cr] = v4.z;
      xs[kq * 4 + 3][4 * (rb ^ ((kq * 4 + 3) & 3)) + cr] = v4.w;
    }
#pragma unroll
    for (int i = 0; i < 4; ++i) {
      int idx = tid + i * 256;
      int v = idx >> 4, kq = idx & 15;
      float4 v4 = *(const float4*)(U + (size_t)(v0g + v) * 128 + k0 + kq * 4);
      int vb = v >> 2, cv = v & 3;
      us[kq * 4 + 0][4 * (vb ^ ((kq * 4 + 0) & 3)) + cv] = v4.x;
      us[kq * 4 + 1][4 * (vb ^ ((kq * 4 + 1) & 3)) + cv] = v4.y;
      us[kq * 4 + 2][4 * (vb ^ ((kq * 4 + 2) & 3)) + cv] = v4.z;
      us[kq * 4 + 3][4 * (vb ^ ((kq * 4 + 3) & 3)) + cv] = v4.w;
    }
    __syncthreads();
#pragma unroll 4
    for (int k = 0; k < 64; ++k) {
      float4 xr = *(const float4*)&xs[k][4 * (tr ^ (k & 3))];
      float4 ur = *(const float4*)&us[k][4 * (tc ^ (k & 3))];
      float xa[4] = {xr.x, xr.y, xr.z, xr.w};
      float ua[4] = {ur.x, ur.y, ur.z, ur.w};
#pragma unroll
      for (int i = 0; i < 4; ++i)
#pragma unroll
        for (int j = 0; j < 4; ++j) acc[i][j] = fmaf(xa[i], ua[j], acc[i][j]);
    }
    __syncthreads();
  }
  // Uk16[b][v][w], v = v0g + tc*4 + j, w = w0 + tr*4 + i
#pragma unroll
  for (int j = 0; j < 4; ++j) {
    ushort4 o;
    o.x = f2bf(acc[0][j]); o.y = f2bf(acc[1][j]);
    o.z = f2bf(acc[2][j]); o.w = f2bf(acc[3][j]);
    *(ushort4*)(Uk16 + ((size_t)b * 128 + v0g + tc * 4 + j) * 512 + w0 + tr * 4) = o;
  }
}

// ---------------- per-step attention: Wq, e, softmax, weight-out, ctx ----------------
__global__ __launch_bounds__(512) void attn_step(const ushort* __restrict__ Uk16,
    const ushort* __restrict__ x16, const float* __restrict__ s, const float* __restrict__ c,
    const float* __restrict__ WT, const float* __restrict__ V,
    float* __restrict__ ctx, float* __restrict__ wout, int t)
{
  __shared__ float q[512];
  __shared__ float wqp[4][128];
  __shared__ float wq[128];
  __shared__ float vv[128];
  __shared__ float watt[512];
  __shared__ float red[16];
  __shared__ float scratch[4096];   // epart[8][512] then cpart[32][128], bank-swizzled
  int tid = threadIdx.x;
  int b = blockIdx.x;

  q[tid] = (tid < 256) ? s[b * 256 + tid] : c[b * 256 + (tid - 256)];
  if (tid < 128) vv[tid] = V[tid];
  __syncthreads();

  // Wq[v] = sum_j q[j] * W[v][j], 4-way split over j
  {
    int v = tid & 127, p = tid >> 7;
    float a = 0.f;
    const float* wtp = WT + (size_t)(p * 128) * 128 + v;
#pragma unroll 4
    for (int j = 0; j < 128; ++j) a = fmaf(q[p * 128 + j], wtp[j * 128], a);
    wqp[p][v] = a;
  }
  __syncthreads();
  if (tid < 128) wq[tid] = wqp[0][tid] + wqp[1][tid] + wqp[2][tid] + wqp[3][tid];
  __syncthreads();

  // e[w] = sum_v vv[v]*tanh(wq[v] + Uk[b][v][w]); vectorized 8 w per thread, 16 v per vg
  {
    int vg = tid >> 6, wc = tid & 63;
    float a8[8];
#pragma unroll
    for (int i = 0; i < 8; ++i) a8[i] = 0.f;
    const ushort* up = Uk16 + ((size_t)b * 128 + vg * 16) * 512 + wc * 8;
#pragma unroll 4
    for (int vi = 0; vi < 16; ++vi) {
      uint4 raw = *(const uint4*)(up + (size_t)vi * 512);
      float wqv = wq[vg * 16 + vi];
      float vvv = vv[vg * 16 + vi];
      a8[0] = fmaf(vvv, tanh_fast(wqv + bflo(raw.x)), a8[0]);
      a8[1] = fmaf(vvv, tanh_fast(wqv + bfhi(raw.x)), a8[1]);
      a8[2] = fmaf(vvv, tanh_fast(wqv + bflo(raw.y)), a8[2]);
      a8[3] = fmaf(vvv, tanh_fast(wqv + bfhi(raw.y)), a8[3]);
      a8[4] = fmaf(vvv, tanh_fast(wqv + bflo(raw.z)), a8[4]);
      a8[5] = fmaf(vvv, tanh_fast(wqv + bfhi(raw.z)), a8[5]);
      a8[6] = fmaf(vvv, tanh_fast(wqv + bflo(raw.w)), a8[6]);
      a8[7] = fmaf(vvv, tanh_fast(wqv + bfhi(raw.w)), a8[7]);
    }
    int rot = (wc + (wc >> 3)) & 7;
    int sbase = vg * 512 + wc * 8;
#pragma unroll
    for (int i = 0; i < 8; ++i) scratch[sbase + ((i + rot) & 7)] = a8[i];
  }
  __syncthreads();
  float e = 0.f;
  {
    int addr = (tid & ~7) + ((tid + (tid >> 3) + (tid >> 6)) & 7);
#pragma unroll
    for (int g = 0; g < 8; ++g) e += scratch[g * 512 + addr];
  }

  // softmax over 512 threads
  float m = e;
#pragma unroll
  for (int o = 32; o > 0; o >>= 1) m = fmaxf(m, __shfl_xor(m, o));
  if ((tid & 63) == 0) red[tid >> 6] = m;
  __syncthreads();
  float M = red[0];
#pragma unroll
  for (int i2 = 1; i2 < 8; ++i2) M = fmaxf(M, red[i2]);
  float p = __expf(e - M);
  float wsum = p;
#pragma unroll
  for (int o = 32; o > 0; o >>= 1) wsum += __shfl_xor(wsum, o);
  if ((tid & 63) == 0) red[8 + (tid >> 6)] = wsum;
  __syncthreads();
  float S = red[8] + red[9] + red[10] + red[11] + red[12] + red[13] + red[14] + red[15];
  float wv = p / S;
  watt[tid] = wv;
  wout[(size_t)b * PLENN * 512 + (size_t)t * 512 + tid] = wv;
  __syncthreads();

  // ctx[d] = sum_w watt[w]*x[b][w][d]; 8 d per thread, 16 w per wchunk
  {
    int dg = tid & 15, wch = tid >> 4;
    float a8[8];
#pragma unroll
    for (int i = 0; i < 8; ++i) a8[i] = 0.f;
    const ushort* xp = x16 + ((size_t)b * 512 + wch * 16) * 128 + dg * 8;
#pragma unroll 4
    for (int wi = 0; wi < 16; ++wi) {
      uint4 raw = *(const uint4*)(xp + (size_t)wi * 128);
      float wgt = watt[wch * 16 + wi];
      a8[0] = fmaf(wgt, bflo(raw.x), a8[0]);
      a8[1] = fmaf(wgt, bfhi(raw.x), a8[1]);
      a8[2] = fmaf(wgt, bflo(raw.y), a8[2]);
      a8[3] = fmaf(wgt, bfhi(raw.y), a8[3]);
      a8[4] = fmaf(wgt, bflo(raw.z), a8[4]);
      a8[5] = fmaf(wgt, bfhi(raw.z), a8[5]);
      a8[6] = fmaf(wgt, bflo(raw.w), a8[6]);
      a8[7] = fmaf(wgt, bfhi(raw.w), a8[7]);
    }
    int rot = (dg + wch) & 7;
    int sbase = wch * 128 + dg * 8;
#pragma unroll
    for (int i = 0; i < 8; ++i) scratch[sbase + ((i + rot) & 7)] = a8[i];
  }
  __syncthreads();
  if (tid < 128) {
    float a = 0.f;
    int base = tid & ~7;
#pragma unroll 8
    for (int k = 0; k < 32; ++k)
      a += scratch[k * 128 + base + ((tid + (tid >> 3) + k) & 7)];
    ctx[b * 128 + tid] = a;
  }
}

// ---------------- per-step gates GEMM: [y|ctx|s](512x448) @ WihT(448x1024), split-K x2 ----------------
__global__ __launch_bounds__(256) void gates_gemm(const float* __restrict__ y,
    const float* __restrict__ ctx, const float* __restrict__ s,
    const float* __restrict__ WihT, const float* __restrict__ bias,
    float* __restrict__ g0, float* __restrict__ g1)
{
  __shared__ float As[32][68];  // [k][r]
  __shared__ float Bs[32][68];  // [k][c]
  int tid = threadIdx.x;
  int bm = blockIdx.x;   // 0..7
  int bn = blockIdx.y;   // 0..15
  int kz = blockIdx.z;   // 0..1
  int tr = tid & 15, tc = tid >> 4;
  float acc[4][4];
#pragma unroll
  for (int i = 0; i < 4; ++i)
#pragma unroll
    for (int j = 0; j < 4; ++j) acc[i][j] = 0.f;

  for (int kt = 0; kt < 7; ++kt) {
    int k0 = kz * 224 + kt * 32;
    const float* Ab; int stride, off;
    if (k0 < 64)       { Ab = y;   stride = 64;  off = 0; }
    else if (k0 < 192) { Ab = ctx; stride = 128; off = 64; }
    else               { Ab = s;   stride = 256; off = 192; }
#pragma unroll
    for (int i = 0; i < 8; ++i) {
      int idx = tid + i * 256;        // 0..2047
      int r = idx >> 5, kk = idx & 31;
      As[kk][r] = Ab[(size_t)(bm * 64 + r) * stride + (k0 - off) + kk];
    }
#pragma unroll
    for (int i = 0; i < 8; ++i) {
      int idx = tid + i * 256;
      int kk = idx >> 6, cc = idx & 63;
      Bs[kk][cc] = WihT[(size_t)(k0 + kk) * 1024 + bn * 64 + cc];
    }
    __syncthreads();
#pragma unroll 8
    for (int kk = 0; kk < 32; ++kk) {
      float a4[4], b4[4];
      *(float4*)a4 = *(const float4*)&As[kk][tr * 4];
      *(float4*)b4 = *(const float4*)&Bs[kk][tc * 4];
#pragma unroll
      for (int i = 0; i < 4; ++i)
#pragma unroll
        for (int j = 0; j < 4; ++j) acc[i][j] = fmaf(a4[i], b4[j], acc[i][j]);
    }
    __syncthreads();
  }
  float* dst = kz ? g1 : g0;
#pragma unroll
  for (int i = 0; i < 4; ++i) {
    int bb = bm * 64 + tr * 4 + i;
    int g  = bn * 64 + tc * 4;
    float4 o4;
    o4.x = acc[i][0] + (kz == 0 ? bias[g + 0] : 0.f);
    o4.y = acc[i][1] + (kz == 0 ? bias[g + 1] : 0.f);
    o4.z = acc[i][2] + (kz == 0 ? bias[g + 2] : 0.f);
    o4.w = acc[i][3] + (kz == 0 ? bias[g + 3] : 0.f);
    *(float4*)(dst + (size_t)bb * 1024 + g) = o4;
  }
}

// ---------------- per-step LSTM elementwise + y = s_new @ Wd^T + bd ----------------
__global__ __launch_bounds__(256) void lstm_step(const float* __restrict__ g0,
    const float* __restrict__ g1, float* __restrict__ s, float* __restrict__ c,
    float* __restrict__ y, const float* __restrict__ Wdt, const float* __restrict__ bd,
    float* __restrict__ outy, int t)
{
  __shared__ float ssh[256];
  int b = blockIdx.x, h = threadIdx.x;
  size_t gb = (size_t)b * 1024;
  float gi = g0[gb + h]       + g1[gb + h];
  float gf = g0[gb + 256 + h] + g1[gb + 256 + h];
  float gg = g0[gb + 512 + h] + g1[gb + 512 + h];
  float go = g0[gb + 768 + h] + g1[gb + 768 + h];
  float cv = c[b * 256 + h];
  float cn = sigmoid_fast(gf) * cv + sigmoid_fast(gi) * tanh_fast(gg);
  float sn = sigmoid_fast(go) * tanh_fast(cn);
  c[b * 256 + h] = cn;
  s[b * 256 + h] = sn;
  ssh[h] = sn;
  __syncthreads();
  if (h < 64) {
    float a = bd[h];
#pragma unroll 4
    for (int k = 0; k < 256; ++k) a = fmaf(ssh[k], Wdt[k * 64 + h], a);
    y[b * 64 + h] = a;
    outy[(size_t)b * PLENN * 64 + (size_t)t * 64 + h] = a;
  }
}

extern "C" void kernel_launch(void* const* d_in, const int* in_sizes, int n_in,
                              void* d_out, int out_size, void* d_ws, size_t ws_size,
                              hipStream_t stream)
{
  (void)in_sizes; (void)n_in; (void)out_size; (void)ws_size;
  const float* x    = (const float*)d_in[0];
  const float* V    = (const float*)d_in[2];
  const float* W    = (const float*)d_in[3];
  const float* U    = (const float*)d_in[4];
  const float* W_ih = (const float*)d_in[5];
  const float* W_hh = (const float*)d_in[6];
  const float* b_ih = (const float*)d_in[7];
  const float* b_hh = (const float*)d_in[8];
  const float* Wd   = (const float*)d_in[9];
  const float* bd   = (const float*)d_in[10];

  float* out  = (float*)d_out;
  float* outy = out;                                   // predict_y (B,64,64)
  float* outw = out + (size_t)BB * PLENN * DOUTN;      // weight    (B,64,512)

  float* ws = (float*)d_ws;
  size_t o = 0;
  ushort* Uk16 = (ushort*)(ws + o); o += (size_t)BB * DIN * WINN / 2;  // 67 MB
  ushort* x16  = (ushort*)(ws + o); o += (size_t)BB * WINN * DIN / 2;  // 67 MB
  float* WT   = ws + o; o += 512 * 128;
  float* WihT = ws + o; o += 448 * 1024;
  float* Wdt  = ws + o; o += 256 * 64;
  float* bias = ws + o; o += 1024;
  float* sbuf = ws + o; o += (size_t)BB * HIDN;
  float* cbuf = ws + o; o += (size_t)BB * HIDN;
  float* ybuf = ws + o; o += (size_t)BB * DOUTN;
  float* ctx  = ws + o; o += (size_t)BB * DIN;
  float* g0   = ws + o; o += (size_t)BB * G4;
  float* g1   = ws + o; o += (size_t)BB * G4;

  hipMemsetAsync(sbuf, 0, (size_t)BB * HIDN * sizeof(float), stream);
  hipMemsetAsync(cbuf, 0, (size_t)BB * HIDN * sizeof(float), stream);
  hipMemsetAsync(ybuf, 0, (size_t)BB * DOUTN * sizeof(float), stream);

  prep_weights<<<1792, 256, 0, stream>>>(W, W_ih, W_hh, b_ih, b_hh, Wd, WT, WihT, Wdt, bias);
  convert_x<<<16384, 256, 0, stream>>>(x, x16);
  compute_uk<<<8192, 256, 0, stream>>>(x, U, Uk16);

  for (int t = 0; t < PLENN; ++t) {
    attn_step<<<BB, 512, 0, stream>>>(Uk16, x16, sbuf, cbuf, WT, V, ctx, outw, t);
    gates_gemm<<<dim3(8, 16, 2), 256, 0, stream>>>(ybuf, ctx, sbuf, WihT, bias, g0, g1);
    lstm_step<<<BB, 256, 0, stream>>>(g0, g1, sbuf, cbuf, ybuf, Wdt, bd, outy, t);
  }
}

// Round 3
// 4349.807 us; speedup vs baseline: 1.7894x; 1.4449x over previous
//
#include <hip/hip_runtime.h>
#include <cstdint>
#include <cstddef>

#define BB    512
#define WINN  512
#define DIN   128
#define HIDN  256
#define DOUTN 64
#define PLENN 64
#define G4    1024   // 4*HID

__device__ __forceinline__ float tanh_fast(float xx) {
  float e = __expf(2.0f * xx);
  return 1.0f - 2.0f * __builtin_amdgcn_rcpf(e + 1.0f);
}
__device__ __forceinline__ float sigmoid_fast(float xx) {
  return __builtin_amdgcn_rcpf(1.0f + __expf(-xx));
}
__device__ __forceinline__ ushort f2bf(float f) {
  uint32_t u = __float_as_uint(f);
  return (ushort)((u + 0x7fffu + ((u >> 16) & 1u)) >> 16);
}
__device__ __forceinline__ float bflo(uint32_t u) { return __uint_as_float(u << 16); }
__device__ __forceinline__ float bfhi(uint32_t u) { return __uint_as_float(u & 0xffff0000u); }

// ---------------- one-time weight prep ----------------
__global__ void prep_weights(const float* __restrict__ W, const float* __restrict__ W_ih,
                             const float* __restrict__ W_hh, const float* __restrict__ b_ih,
                             const float* __restrict__ b_hh, const float* __restrict__ Wd,
                             const float* __restrict__ V,
                             float* __restrict__ WT, float* __restrict__ WihT,
                             float* __restrict__ Wdt, float* __restrict__ bias,
                             float* __restrict__ m2vv)
{
  int i = blockIdx.x * 256 + threadIdx.x;
  if (i < 512 * 128) { int j = i >> 7, v = i & 127; WT[i] = W[v * 512 + j]; }
  if (i < 448 * 1024) {
    int k = i >> 10, g = i & 1023;
    WihT[i] = (k < 192) ? W_ih[g * 192 + k] : W_hh[g * 256 + (k - 192)];
  }
  if (i < 256 * 64) { int h = i >> 6, d = i & 63; Wdt[i] = Wd[d * 256 + h]; }
  if (i < 1024) bias[i] = b_ih[i] + b_hh[i];
  if (i < 128) m2vv[i] = -2.0f * V[i];
}

// ---------------- one-time x -> bf16 copy ----------------
__global__ __launch_bounds__(256) void convert_x(const float* __restrict__ x,
                                                 ushort* __restrict__ x16)
{
  size_t i = ((size_t)blockIdx.x * 256 + threadIdx.x) * 8;
  float4 a = *(const float4*)(x + i);
  float4 b = *(const float4*)(x + i + 4);
  uint4 o;
  o.x = (uint32_t)f2bf(a.x) | ((uint32_t)f2bf(a.y) << 16);
  o.y = (uint32_t)f2bf(a.z) | ((uint32_t)f2bf(a.w) << 16);
  o.z = (uint32_t)f2bf(b.x) | ((uint32_t)f2bf(b.y) << 16);
  o.w = (uint32_t)f2bf(b.z) | ((uint32_t)f2bf(b.w) << 16);
  *(uint4*)(x16 + i) = o;
}

// ---------------- one-time Uk = einsum('vd,bwd->bvw'), bf16 output ----------------
__global__ __launch_bounds__(256) void compute_uk(const float* __restrict__ x,
                                                  const float* __restrict__ U,
                                                  ushort* __restrict__ Uk16)
{
  __shared__ float xs[64][68];
  __shared__ float us[64][68];
  int tid = threadIdx.x;
  int rblk = blockIdx.x >> 1;
  int vhalf = blockIdx.x & 1;
  int r0g = rblk * 64;
  int v0g = vhalf * 64;
  int b  = r0g >> 9;
  int w0 = r0g & 511;
  int tr = tid & 15, tc = tid >> 4;
  float acc[4][4];
#pragma unroll
  for (int i = 0; i < 4; ++i)
#pragma unroll
    for (int j = 0; j < 4; ++j) acc[i][j] = 0.f;

  for (int ks = 0; ks < 2; ++ks) {
    int k0 = ks * 64;
#pragma unroll
    for (int i = 0; i < 4; ++i) {
      int idx = tid + i * 256;
      int r = idx >> 4, kq = idx & 15;
      float4 v4 = *(const float4*)(x + (size_t)(r0g + r) * 128 + k0 + kq * 4);
      int rb = r >> 2, cr = r & 3;
      xs[kq * 4 + 0][4 * (rb ^ ((kq * 4 + 0) & 3)) + cr] = v4.x;
      xs[kq * 4 + 1][4 * (rb ^ ((kq * 4 + 1) & 3)) + cr] = v4.y;
      xs[kq * 4 + 2][4 * (rb ^ ((kq * 4 + 2) & 3)) + cr] = v4.z;
      xs[kq * 4 + 3][4 * (rb ^ ((kq * 4 + 3) & 3)) + cr] = v4.w;
    }
#pragma unroll
    for (int i = 0; i < 4; ++i) {
      int idx = tid + i * 256;
      int v = idx >> 4, kq = idx & 15;
      float4 v4 = *(const float4*)(U + (size_t)(v0g + v) * 128 + k0 + kq * 4);
      int vb = v >> 2, cv = v & 3;
      us[kq * 4 + 0][4 * (vb ^ ((kq * 4 + 0) & 3)) + cv] = v4.x;
      us[kq * 4 + 1][4 * (vb ^ ((kq * 4 + 1) & 3)) + cv] = v4.y;
      us[kq * 4 + 2][4 * (vb ^ ((kq * 4 + 2) & 3)) + cv] = v4.z;
      us[kq * 4 + 3][4 * (vb ^ ((kq * 4 + 3) & 3)) + cv] = v4.w;
    }
    __syncthreads();
#pragma unroll 4
    for (int k = 0; k < 64; ++k) {
      float4 xr = *(const float4*)&xs[k][4 * (tr ^ (k & 3))];
      float4 ur = *(const float4*)&us[k][4 * (tc ^ (k & 3))];
      float xa[4] = {xr.x, xr.y, xr.z, xr.w};
      float ua[4] = {ur.x, ur.y, ur.z, ur.w};
#pragma unroll
      for (int i = 0; i < 4; ++i)
#pragma unroll
        for (int j = 0; j < 4; ++j) acc[i][j] = fmaf(xa[i], ua[j], acc[i][j]);
    }
    __syncthreads();
  }
#pragma unroll
  for (int j = 0; j < 4; ++j) {
    ushort4 o;
    o.x = f2bf(acc[0][j]); o.y = f2bf(acc[1][j]);
    o.z = f2bf(acc[2][j]); o.w = f2bf(acc[3][j]);
    *(ushort4*)(Uk16 + ((size_t)b * 128 + v0g + tc * 4 + j) * 512 + w0 + tr * 4) = o;
  }
}

// ---------------- fused per-step: lstm(t-1) + wq + e + softmax + ctx ----------------
__global__ __launch_bounds__(512, 6) void attn_fused(const ushort* __restrict__ Uk16,
    const ushort* __restrict__ x16, float* __restrict__ s, float* __restrict__ c,
    float* __restrict__ y, const float* __restrict__ g0, const float* __restrict__ g1,
    const float* __restrict__ WT, const float* __restrict__ Wdt,
    const float* __restrict__ bd, const float* __restrict__ m2vv_g,
    float* __restrict__ ctx, float* __restrict__ wout, float* __restrict__ outy, int t)
{
  __shared__ float q_sh[512];     // [s(256); c(256)]
  __shared__ float twq[128];      // 2*wq[v]
  __shared__ float m2vv[128];     // -2*V[v]
  __shared__ float watt[512];
  __shared__ float red[16];
  __shared__ float cp2[544];      // 4x136 second-stage ctx partials
  __shared__ float scratch[4096];
  int tid = threadIdx.x;
  int b = blockIdx.x;

  // ---- phase A: lstm(t-1) -> s,c (+ q_sh), or zeros at t==0 ----
  if (t > 0) {
    if (tid < 256) {
      int h = tid;
      size_t gb = (size_t)b * 1024;
      float gi = g0[gb + h]       + g1[gb + h];
      float gf = g0[gb + 256 + h] + g1[gb + 256 + h];
      float gg = g0[gb + 512 + h] + g1[gb + 512 + h];
      float go = g0[gb + 768 + h] + g1[gb + 768 + h];
      float cv = c[b * 256 + h];
      float cn = sigmoid_fast(gf) * cv + sigmoid_fast(gi) * tanh_fast(gg);
      float sn = sigmoid_fast(go) * tanh_fast(cn);
      c[b * 256 + h] = cn;
      s[b * 256 + h] = sn;
      q_sh[h] = sn;
      q_sh[256 + h] = cn;
    }
  } else {
    if (tid < 256) { q_sh[tid] = 0.f; q_sh[256 + tid] = 0.f; }
  }
  if (tid >= 256 && tid < 384) m2vv[tid - 256] = m2vv_g[tid - 256];
  __syncthreads();

  // ---- phase A2: y = s_new @ Wd^T + bd (8-way split over h), t>0 only ----
  if (t > 0) {
    int p = tid >> 6, d = tid & 63;
    float a = 0.f;
    const float* wdp = Wdt + (size_t)(p * 32) * 64 + d;
#pragma unroll 4
    for (int hh = 0; hh < 32; ++hh) a = fmaf(q_sh[p * 32 + hh], wdp[hh * 64], a);
    scratch[p * 68 + d] = a;
  }
  // ---- phase B1: wq partials (4-way split over j), uses scratch[1024..] ----
  {
    int p = tid >> 7, v = tid & 127;
    float a = 0.f;
    const float* wtp = WT + (size_t)(p * 128) * 128 + v;
#pragma unroll 4
    for (int j = 0; j < 128; ++j) a = fmaf(q_sh[p * 128 + j], wtp[j * 128], a);
    scratch[1024 + p * 132 + v] = a;
  }
  __syncthreads();
  // finalize y (t>0) and twq in parallel thread ranges
  if (t > 0 && tid < 64) {
    float a = bd[tid];
#pragma unroll
    for (int p = 0; p < 8; ++p) a += scratch[p * 68 + tid];
    y[b * 64 + tid] = a;
    outy[(size_t)b * PLENN * 64 + (size_t)(t - 1) * 64 + tid] = a;
  }
  if (tid >= 128 && tid < 256) {
    int v = tid - 128;
    float wq = scratch[1024 + v] + scratch[1024 + 132 + v] +
               scratch[1024 + 264 + v] + scratch[1024 + 396 + v];
    twq[v] = 2.0f * wq;
  }
  __syncthreads();

  // ---- phase C: e-partials; thread (vg=tid>>6, wc=tid&63) does 16 v x 8 w ----
  {
    int vg = tid >> 6, wc = tid & 63;
    float a8[8];
#pragma unroll
    for (int i = 0; i < 8; ++i) a8[i] = 0.f;
    const ushort* up = Uk16 + ((size_t)b * 128 + vg * 16) * 512 + wc * 8;
#pragma unroll 4
    for (int vi = 0; vi < 16; ++vi) {
      uint4 raw = *(const uint4*)(up + (size_t)vi * 512);
      float tq = twq[vg * 16 + vi];
      float mv = m2vv[vg * 16 + vi];
      // tanh contribution: mv * rcp(exp(2u+2wq)+1)  (constant part cancels in softmax)
      a8[0] = fmaf(mv, __builtin_amdgcn_rcpf(__expf(fmaf(bflo(raw.x), 2.f, tq)) + 1.f), a8[0]);
      a8[1] = fmaf(mv, __builtin_amdgcn_rcpf(__expf(fmaf(bfhi(raw.x), 2.f, tq)) + 1.f), a8[1]);
      a8[2] = fmaf(mv, __builtin_amdgcn_rcpf(__expf(fmaf(bflo(raw.y), 2.f, tq)) + 1.f), a8[2]);
      a8[3] = fmaf(mv, __builtin_amdgcn_rcpf(__expf(fmaf(bfhi(raw.y), 2.f, tq)) + 1.f), a8[3]);
      a8[4] = fmaf(mv, __builtin_amdgcn_rcpf(__expf(fmaf(bflo(raw.z), 2.f, tq)) + 1.f), a8[4]);
      a8[5] = fmaf(mv, __builtin_amdgcn_rcpf(__expf(fmaf(bfhi(raw.z), 2.f, tq)) + 1.f), a8[5]);
      a8[6] = fmaf(mv, __builtin_amdgcn_rcpf(__expf(fmaf(bflo(raw.w), 2.f, tq)) + 1.f), a8[6]);
      a8[7] = fmaf(mv, __builtin_amdgcn_rcpf(__expf(fmaf(bfhi(raw.w), 2.f, tq)) + 1.f), a8[7]);
    }
    int rot = (wc + (wc >> 3)) & 7;
    int sbase = vg * 512 + wc * 8;
#pragma unroll
    for (int i = 0; i < 8; ++i) scratch[sbase + ((i + rot) & 7)] = a8[i];
  }
  __syncthreads();
  float e = 0.f;
  {
    int addr = (tid & ~7) + ((tid + (tid >> 3) + (tid >> 6)) & 7);
#pragma unroll
    for (int g = 0; g < 8; ++g) e += scratch[g * 512 + addr];
  }

  // ---- softmax over 512 w ----
  float m = e;
#pragma unroll
  for (int o = 32; o > 0; o >>= 1) m = fmaxf(m, __shfl_xor(m, o));
  if ((tid & 63) == 0) red[tid >> 6] = m;
  __syncthreads();
  float M = red[0];
#pragma unroll
  for (int i2 = 1; i2 < 8; ++i2) M = fmaxf(M, red[i2]);
  float p = __expf(e - M);
  float wsum = p;
#pragma unroll
  for (int o = 32; o > 0; o >>= 1) wsum += __shfl_xor(wsum, o);
  if ((tid & 63) == 0) red[8 + (tid >> 6)] = wsum;
  __syncthreads();
  float S = red[8] + red[9] + red[10] + red[11] + red[12] + red[13] + red[14] + red[15];
  float wv = p * __builtin_amdgcn_rcpf(S);
  watt[tid] = wv;
  wout[(size_t)b * PLENN * 512 + (size_t)t * 512 + tid] = wv;
  __syncthreads();

  // ---- phase E: ctx partials; thread (wch=tid>>4, dg=tid&15) does 16 w x 8 d ----
  {
    int dg = tid & 15, wch = tid >> 4;
    float a8[8];
#pragma unroll
    for (int i = 0; i < 8; ++i) a8[i] = 0.f;
    const ushort* xp = x16 + ((size_t)b * 512 + wch * 16) * 128 + dg * 8;
#pragma unroll 4
    for (int wi = 0; wi < 16; ++wi) {
      uint4 raw = *(const uint4*)(xp + (size_t)wi * 128);
      float wgt = watt[wch * 16 + wi];
      a8[0] = fmaf(wgt, bflo(raw.x), a8[0]);
      a8[1] = fmaf(wgt, bfhi(raw.x), a8[1]);
      a8[2] = fmaf(wgt, bflo(raw.y), a8[2]);
      a8[3] = fmaf(wgt, bfhi(raw.y), a8[3]);
      a8[4] = fmaf(wgt, bflo(raw.z), a8[4]);
      a8[5] = fmaf(wgt, bfhi(raw.z), a8[5]);
      a8[6] = fmaf(wgt, bflo(raw.w), a8[6]);
      a8[7] = fmaf(wgt, bfhi(raw.w), a8[7]);
    }
    int rot = (dg + wch) & 7;
    int sbase = wch * 128 + dg * 8;
#pragma unroll
    for (int i = 0; i < 8; ++i) scratch[sbase + ((i + rot) & 7)] = a8[i];
  }
  __syncthreads();
  // two-stage reduce: 512 threads sum 8 chunks each, then 128 sum 4
  {
    int p = tid >> 7, d = tid & 127;
    float a = 0.f;
#pragma unroll
    for (int k = 0; k < 8; ++k) {
      int wch = p * 8 + k;
      a += scratch[wch * 128 + (d & ~7) + (((d & 7) + (d >> 3) + wch) & 7)];
    }
    cp2[p * 136 + d] = a;
  }
  __syncthreads();
  if (tid < 128)
    ctx[b * 128 + tid] = cp2[tid] + cp2[136 + tid] + cp2[272 + tid] + cp2[408 + tid];
}

// ---------------- per-step gates GEMM: 32x64 tiles, 512 blocks ----------------
__global__ __launch_bounds__(256) void gates_gemm(const float* __restrict__ y,
    const float* __restrict__ ctx, const float* __restrict__ s,
    const float* __restrict__ WihT, const float* __restrict__ bias,
    float* __restrict__ g0, float* __restrict__ g1)
{
  __shared__ float As[32][36];  // [k][r]
  __shared__ float Bs[32][68];  // [k][c]
  int tid = threadIdx.x;
  int bm = blockIdx.x;   // 0..15 (32 rows each)
  int bn = blockIdx.y;   // 0..15 (64 cols each)
  int kz = blockIdx.z;   // 0..1
  int tr = tid & 15, tc = tid >> 4;
  float acc[2][4];
#pragma unroll
  for (int i = 0; i < 2; ++i)
#pragma unroll
    for (int j = 0; j < 4; ++j) acc[i][j] = 0.f;

  for (int kt = 0; kt < 7; ++kt) {
    int k0 = kz * 224 + kt * 32;
    const float* Ab; int stride, off;
    if (k0 < 64)       { Ab = y;   stride = 64;  off = 0; }
    else if (k0 < 192) { Ab = ctx; stride = 128; off = 64; }
    else               { Ab = s;   stride = 256; off = 192; }
#pragma unroll
    for (int i = 0; i < 4; ++i) {
      int idx = tid + i * 256;        // 0..1023
      int r = idx >> 5, kk = idx & 31;
      As[kk][r] = Ab[(size_t)(bm * 32 + r) * stride + (k0 - off) + kk];
    }
#pragma unroll
    for (int i = 0; i < 8; ++i) {
      int idx = tid + i * 256;        // 0..2047
      int kk = idx >> 6, cc = idx & 63;
      Bs[kk][cc] = WihT[(size_t)(k0 + kk) * 1024 + bn * 64 + cc];
    }
    __syncthreads();
#pragma unroll 8
    for (int kk = 0; kk < 32; ++kk) {
      float2 a2 = *(const float2*)&As[kk][tr * 2];
      float4 b4 = *(const float4*)&Bs[kk][tc * 4];
      acc[0][0] = fmaf(a2.x, b4.x, acc[0][0]);
      acc[0][1] = fmaf(a2.x, b4.y, acc[0][1]);
      acc[0][2] = fmaf(a2.x, b4.z, acc[0][2]);
      acc[0][3] = fmaf(a2.x, b4.w, acc[0][3]);
      acc[1][0] = fmaf(a2.y, b4.x, acc[1][0]);
      acc[1][1] = fmaf(a2.y, b4.y, acc[1][1]);
      acc[1][2] = fmaf(a2.y, b4.z, acc[1][2]);
      acc[1][3] = fmaf(a2.y, b4.w, acc[1][3]);
    }
    __syncthreads();
  }
  float* dst = kz ? g1 : g0;
#pragma unroll
  for (int i = 0; i < 2; ++i) {
    int bb = bm * 32 + tr * 2 + i;
    int g  = bn * 64 + tc * 4;
    float4 o4;
    o4.x = acc[i][0] + (kz == 0 ? bias[g + 0] : 0.f);
    o4.y = acc[i][1] + (kz == 0 ? bias[g + 1] : 0.f);
    o4.z = acc[i][2] + (kz == 0 ? bias[g + 2] : 0.f);
    o4.w = acc[i][3] + (kz == 0 ? bias[g + 3] : 0.f);
    *(float4*)(dst + (size_t)bb * 1024 + g) = o4;
  }
}

// ---------------- tail: final lstm (t=63) + y ----------------
__global__ __launch_bounds__(256) void lstm_tail(const float* __restrict__ g0,
    const float* __restrict__ g1, float* __restrict__ s, float* __restrict__ c,
    const float* __restrict__ Wdt, const float* __restrict__ bd,
    float* __restrict__ outy, int t)
{
  __shared__ float ssh[256];
  int b = blockIdx.x, h = threadIdx.x;
  size_t gb = (size_t)b * 1024;
  float gi = g0[gb + h]       + g1[gb + h];
  float gf = g0[gb + 256 + h] + g1[gb + 256 + h];
  float gg = g0[gb + 512 + h] + g1[gb + 512 + h];
  float go = g0[gb + 768 + h] + g1[gb + 768 + h];
  float cv = c[b * 256 + h];
  float cn = sigmoid_fast(gf) * cv + sigmoid_fast(gi) * tanh_fast(gg);
  float sn = sigmoid_fast(go) * tanh_fast(cn);
  ssh[h] = sn;
  __syncthreads();
  if (h < 64) {
    float a = bd[h];
#pragma unroll 4
    for (int k = 0; k < 256; ++k) a = fmaf(ssh[k], Wdt[k * 64 + h], a);
    outy[(size_t)b * PLENN * 64 + (size_t)t * 64 + h] = a;
  }
}

extern "C" void kernel_launch(void* const* d_in, const int* in_sizes, int n_in,
                              void* d_out, int out_size, void* d_ws, size_t ws_size,
                              hipStream_t stream)
{
  (void)in_sizes; (void)n_in; (void)out_size; (void)ws_size;
  const float* x    = (const float*)d_in[0];
  const float* V    = (const float*)d_in[2];
  const float* W    = (const float*)d_in[3];
  const float* U    = (const float*)d_in[4];
  const float* W_ih = (const float*)d_in[5];
  const float* W_hh = (const float*)d_in[6];
  const float* b_ih = (const float*)d_in[7];
  const float* b_hh = (const float*)d_in[8];
  const float* Wd   = (const float*)d_in[9];
  const float* bd   = (const float*)d_in[10];

  float* out  = (float*)d_out;
  float* outy = out;                                   // predict_y (B,64,64)
  float* outw = out + (size_t)BB * PLENN * DOUTN;      // weight    (B,64,512)

  float* ws = (float*)d_ws;
  size_t o = 0;
  ushort* Uk16 = (ushort*)(ws + o); o += (size_t)BB * DIN * WINN / 2;
  ushort* x16  = (ushort*)(ws + o); o += (size_t)BB * WINN * DIN / 2;
  float* WT   = ws + o; o += 512 * 128;
  float* WihT = ws + o; o += 448 * 1024;
  float* Wdt  = ws + o; o += 256 * 64;
  float* bias = ws + o; o += 1024;
  float* m2vv = ws + o; o += 128;
  float* sbuf = ws + o; o += (size_t)BB * HIDN;
  float* cbuf = ws + o; o += (size_t)BB * HIDN;
  float* ybuf = ws + o; o += (size_t)BB * DOUTN;
  float* ctx  = ws + o; o += (size_t)BB * DIN;
  float* g0   = ws + o; o += (size_t)BB * G4;
  float* g1   = ws + o; o += (size_t)BB * G4;

  hipMemsetAsync(sbuf, 0, (size_t)BB * HIDN * sizeof(float), stream);
  hipMemsetAsync(cbuf, 0, (size_t)BB * HIDN * sizeof(float), stream);
  hipMemsetAsync(ybuf, 0, (size_t)BB * DOUTN * sizeof(float), stream);

  prep_weights<<<1792, 256, 0, stream>>>(W, W_ih, W_hh, b_ih, b_hh, Wd, V,
                                         WT, WihT, Wdt, bias, m2vv);
  convert_x<<<16384, 256, 0, stream>>>(x, x16);
  compute_uk<<<8192, 256, 0, stream>>>(x, U, Uk16);

  for (int t = 0; t < PLENN; ++t) {
    attn_fused<<<BB, 512, 0, stream>>>(Uk16, x16, sbuf, cbuf, ybuf, g0, g1,
                                       WT, Wdt, bd, m2vv, ctx, outw, outy, t);
    gates_gemm<<<dim3(16, 16, 2), 256, 0, stream>>>(ybuf, ctx, sbuf, WihT, bias, g0, g1);
  }
  lstm_tail<<<BB, 256, 0, stream>>>(g0, g1, sbuf, cbuf, Wdt, bd, outy, PLENN - 1);
}